// Round 4
// baseline (1739.216 us; speedup 1.0000x reference)
//
#include <hip/hip_runtime.h>

// ---------------- problem constants ----------------
#define T_TOK 8192          // B*S tokens
#define HID   2048
#define FFN_D 4096
#define NEXP  8
#define BM    128           // GEMM M tile (packed pair-rows)
#define CAP_ROWS (T_TOK*2 + BM)          // 16512
#define MAX_TILES (T_TOK*2/BM + NEXP)    // 136 worst-case M tiles

typedef unsigned short u16;
typedef unsigned int   u32;
typedef __attribute__((ext_vector_type(8))) u16    u16x8;
typedef __attribute__((ext_vector_type(8))) __bf16 bf16x8;
typedef __attribute__((ext_vector_type(4))) float  f32x4;

// meta[] int layout inside ws
#define M_CNT 0
#define M_CUR 8
#define M_OFF 16
#define M_NT  24
#define M_TEXP 32
#define M_TM0  192

__device__ __forceinline__ u16 f2bf(float f){   // RNE f32 -> bf16 (bit path, for non-pair sites)
  u32 u = __float_as_uint(f);
  u += 0x7FFFu + ((u >> 16) & 1u);
  return (u16)(u >> 16);
}
__device__ __forceinline__ float bf2f(u16 v){
  return __uint_as_float(((u32)v) << 16);
}

__device__ __forceinline__ void gload16(const void* g, void* l){
  __builtin_amdgcn_global_load_lds((const __attribute__((address_space(1))) u32*)g,
                                   (__attribute__((address_space(3))) u32*)l, 16, 0, 0);
}

// convert 8 f32 (two float4) -> bf16x8 via native casts (compiler emits v_cvt_pk_bf16_f32)
__device__ __forceinline__ bf16x8 cvt8(float4 v0, float4 v1){
  bf16x8 o;
  o[0]=(__bf16)v0.x; o[1]=(__bf16)v0.y; o[2]=(__bf16)v0.z; o[3]=(__bf16)v0.w;
  o[4]=(__bf16)v1.x; o[5]=(__bf16)v1.y; o[6]=(__bf16)v1.z; o[7]=(__bf16)v1.w;
  return o;
}

// ---------------- x -> bf16 ----------------
__global__ __launch_bounds__(256) void moe_cvt(const float* __restrict__ src,
                                               u16* __restrict__ dst){
  size_t i = ((size_t)blockIdx.x * 256 + threadIdx.x) * 8;
  float4 v0 = *(const float4*)(src + i);
  float4 v1 = *(const float4*)(src + i + 4);
  *(bf16x8*)(dst + i) = cvt8(v0, v1);
}

// ---------------- routing: one wave per token ----------------
__global__ __launch_bounds__(256) void moe_route(const float* __restrict__ x,
                                                 const float* __restrict__ gw,
                                                 int* __restrict__ meta,
                                                 int* __restrict__ tok_top,
                                                 float* __restrict__ tok_wt){
  const int wid  = threadIdx.x >> 6;
  const int lane = threadIdx.x & 63;
  const int tok  = blockIdx.x * 4 + wid;
  const float* xr = x + (size_t)tok * HID;

  float s[NEXP];
  #pragma unroll
  for (int e=0;e<NEXP;e++) s[e]=0.f;

  for (int k = lane*4; k < HID; k += 256){
    const float4 xv = *(const float4*)(xr + k);
    #pragma unroll
    for (int e=0;e<NEXP;e++){
      const float4 g = *(const float4*)(gw + e*HID + k);
      s[e] += xv.x*g.x + xv.y*g.y + xv.z*g.z + xv.w*g.w;
    }
  }
  #pragma unroll
  for (int o=32;o;o>>=1){
    #pragma unroll
    for (int e=0;e<NEXP;e++) s[e] += __shfl_xor(s[e], o);
  }
  if (lane==0){
    float m1 = s[0]; int a = 0;
    #pragma unroll
    for (int e=1;e<NEXP;e++) if (s[e] > m1){ m1 = s[e]; a = e; }
    float m2 = -3.0e38f; int b = 0;
    #pragma unroll
    for (int e=0;e<NEXP;e++) if (e != a && s[e] > m2){ m2 = s[e]; b = e; }
    const float r  = __expf(m2 - m1);
    const float wa = 1.f / (1.f + r);
    tok_top[tok*2]   = a;  tok_top[tok*2+1] = b;
    tok_wt[tok*2]    = wa; tok_wt[tok*2+1]  = r * wa;
    atomicAdd(&meta[M_CNT + a], 1);
    atomicAdd(&meta[M_CNT + b], 1);
  }
}

// ---------------- prefix + tile table ----------------
__global__ void moe_prefix(int* __restrict__ meta){
  if (threadIdx.x != 0 || blockIdx.x != 0) return;
  int off = 0, nt = 0;
  for (int e=0;e<NEXP;e++){
    const int c = meta[M_CNT + e];
    meta[M_OFF + e] = off;
    meta[M_CUR + e] = off;
    const int ntE = (c + BM - 1) / BM;
    for (int i=0;i<ntE;i++){ meta[M_TEXP + nt] = e; meta[M_TM0 + nt] = off + i*BM; nt++; }
    off += c;
  }
  meta[M_NT] = nt;
}

// ---------------- scatter (also records inverse map pos_of, aliased on tok_wt) ----------------
__global__ __launch_bounds__(256) void moe_scatter(const int* __restrict__ tok_top,
                                                   float* __restrict__ tok_wt,
                                                   int* __restrict__ meta,
                                                   int* __restrict__ row_tok,
                                                   float* __restrict__ row_w){
  const int i = blockIdx.x * 256 + threadIdx.x;
  const int e = tok_top[i];
  const float w = tok_wt[i];
  const int pos = atomicAdd(&meta[M_CUR + e], 1);
  row_tok[pos] = i >> 1;
  row_w[pos]   = w;
  ((int*)tok_wt)[i] = pos;      // pos_of: safe self-alias (own slot, after read)
}

// ================= up-GEMM: A(xb bf16) via global_load_lds; B(w1/w3 f32) reg-staged =================
// LDS tile layout: [rows][64] bf16 in 16B chunks; logical chunk c of row r at pc = c ^ (r&7).
__global__ __launch_bounds__(256,2) void moe_up_f(
    const u16* __restrict__ xb, const float* __restrict__ w1, const float* __restrict__ w3,
    u16* __restrict__ act, const int* __restrict__ meta,
    const int* __restrict__ row_tok, const float* __restrict__ row_w){
  const int tile = blockIdx.y;
  if (tile >= meta[M_NT]) return;
  const int e      = meta[M_TEXP + tile];
  const int m0     = meta[M_TM0 + tile];
  const int rowEnd = meta[M_OFF + e] + meta[M_CNT + e];
  const int n0     = blockIdx.x * 64;

  __shared__ u16 As[128*64];     // 16 KB
  __shared__ u16 Bs[2*64*64];    // 16 KB (w1 | w3)

  const int t    = threadIdx.x;
  const int lane = t & 63;
  const int wid  = t >> 6;
  const int wm   = wid >> 1, wn = wid & 1;

  // A staging: pre-swizzled global source, linear LDS dest (gload16)
  u32 aoff[4];
  #pragma unroll
  for (int i=0;i<4;i++){
    const int g  = i*256 + t;        // chunk id 0..1023
    const int r  = g >> 3;           // 0..127
    const int pc = g & 7;
    aoff[i] = (u32)row_tok[m0 + r] * HID + (u32)((pc ^ (r & 7)) * 8);
  }
  // B staging: f32 global -> reg -> cvt -> swizzled ds_write
  const size_t eW = (size_t)e * FFN_D * HID;
  const float* w1e = w1 + eW;
  const float* w3e = w3 + eW;
  const float* bsrc[4];
  u16*         bdst[4];
  #pragma unroll
  for (int i=0;i<4;i++){
    const int g  = i*256 + t;
    const int r  = g >> 3;           // 0..127 (0-63: w1 rows, 64-127: w3 rows)
    const int pc = g & 7;
    const int rr = r & 63;
    const float* base = (r < 64) ? w1e : w3e;
    bsrc[i] = base + (size_t)(n0 + rr) * HID + (u32)((pc ^ (rr & 7)) * 8);
    bdst[i] = Bs + r*64 + pc*8;      // physical (swizzled) chunk
  }

  f32x4 accG[4][2], accU[4][2];
  #pragma unroll
  for (int i=0;i<4;i++){
    #pragma unroll
    for (int j=0;j<2;j++){ accG[i][j]=(f32x4)0.f; accU[i][j]=(f32x4)0.f; }
  }

  const int lr = lane & 15;
  const int lq = lane >> 4;

  for (int kk = 0; kk < HID; kk += 64){
    __syncthreads();
    // issue long-latency f32 B loads first
    float4 bv0[4], bv1[4];
    #pragma unroll
    for (int i=0;i<4;i++){
      bv0[i] = *(const float4*)(bsrc[i] + kk);
      bv1[i] = *(const float4*)(bsrc[i] + kk + 4);
    }
    // A direct to LDS
    #pragma unroll
    for (int i=0;i<4;i++)
      gload16(xb + aoff[i] + kk, As + (size_t)(i*256 + wid*64)*8);
    // convert + swizzled LDS write
    #pragma unroll
    for (int i=0;i<4;i++)
      *(bf16x8*)bdst[i] = cvt8(bv0[i], bv1[i]);
    __syncthreads();

    #pragma unroll
    for (int ks=0; ks<2; ks++){
      const int c = ks*4 + lq;
      bf16x8 a[4], bG[2], bU[2];
      #pragma unroll
      for (int mi=0;mi<4;mi++){
        const int r = wm*64 + mi*16 + lr;
        a[mi] = *(const bf16x8*)(As + r*64 + (c ^ (r&7))*8);
      }
      #pragma unroll
      for (int ni=0;ni<2;ni++){
        const int r  = wn*32 + ni*16 + lr;
        const int po = (c ^ (r&7))*8;
        bG[ni] = *(const bf16x8*)(Bs + r*64 + po);
        bU[ni] = *(const bf16x8*)(Bs + 4096 + r*64 + po);
      }
      #pragma unroll
      for (int mi=0;mi<4;mi++){
        #pragma unroll
        for (int ni=0;ni<2;ni++){
          accG[mi][ni] = __builtin_amdgcn_mfma_f32_16x16x32_bf16(a[mi], bG[ni], accG[mi][ni],0,0,0);
          accU[mi][ni] = __builtin_amdgcn_mfma_f32_16x16x32_bf16(a[mi], bU[ni], accU[mi][ni],0,0,0);
        }
      }
    }
  }

  const int l4 = lq * 4;
  #pragma unroll
  for (int mi=0;mi<4;mi++){
    #pragma unroll
    for (int r=0;r<4;r++){
      const int pos = m0 + wm*64 + mi*16 + l4 + r;
      if (pos < rowEnd){
        const float rw = row_w[pos];
        #pragma unroll
        for (int ni=0;ni<2;ni++){
          const int n = n0 + wn*32 + ni*16 + lr;
          const float g = accG[mi][ni][r];
          const float u = accU[mi][ni][r];
          act[(size_t)pos * FFN_D + n] = f2bf(fmaxf(g, 0.f) * u * rw);
        }
      }
    }
  }
}

// ================= down-GEMM: part[pos] = act[pos] @ w2^T; B(w2 f32) reg-staged =================
__global__ __launch_bounds__(256,2) void moe_down_f(
    const u16* __restrict__ act, const float* __restrict__ w2,
    u16* __restrict__ part, const int* __restrict__ meta){
  const int tile = blockIdx.y;
  if (tile >= meta[M_NT]) return;
  const int e      = meta[M_TEXP + tile];
  const int m0     = meta[M_TM0 + tile];
  const int rowEnd = meta[M_OFF + e] + meta[M_CNT + e];
  const int n0     = blockIdx.x * 128;

  __shared__ u16 As[128*64];   // 16 KB
  __shared__ u16 Bs[128*64];   // 16 KB

  const int t    = threadIdx.x;
  const int lane = t & 63;
  const int wid  = t >> 6;
  const int wm   = wid >> 1, wn = wid & 1;

  u32 aoff[4];
  const float* bsrc[4];
  u16*         bdst[4];
  const float* w2e = w2 + (size_t)e * HID * FFN_D;
  #pragma unroll
  for (int i=0;i<4;i++){
    const int g  = i*256 + t;
    const int r  = g >> 3;           // 0..127
    const int pc = g & 7;
    const int c8 = (pc ^ (r & 7)) * 8;
    aoff[i] = (u32)(m0 + r) * FFN_D + (u32)c8;
    bsrc[i] = w2e + (size_t)(n0 + r) * FFN_D + (u32)c8;
    bdst[i] = Bs + r*64 + pc*8;
  }

  f32x4 acc[4][4];
  #pragma unroll
  for (int i=0;i<4;i++){
    #pragma unroll
    for (int j=0;j<4;j++) acc[i][j]=(f32x4)0.f;
  }

  const int lr = lane & 15;
  const int lq = lane >> 4;

  for (int kk = 0; kk < FFN_D; kk += 64){
    __syncthreads();
    float4 bv0[4], bv1[4];
    #pragma unroll
    for (int i=0;i<4;i++){
      bv0[i] = *(const float4*)(bsrc[i] + kk);
      bv1[i] = *(const float4*)(bsrc[i] + kk + 4);
    }
    #pragma unroll
    for (int i=0;i<4;i++)
      gload16(act + aoff[i] + kk, As + (size_t)(i*256 + wid*64)*8);
    #pragma unroll
    for (int i=0;i<4;i++)
      *(bf16x8*)bdst[i] = cvt8(bv0[i], bv1[i]);
    __syncthreads();

    #pragma unroll
    for (int ks=0; ks<2; ks++){
      const int c = ks*4 + lq;
      bf16x8 a[4], b[4];
      #pragma unroll
      for (int mi=0;mi<4;mi++){
        const int r = wm*64 + mi*16 + lr;
        a[mi] = *(const bf16x8*)(As + r*64 + (c ^ (r&7))*8);
      }
      #pragma unroll
      for (int ni=0;ni<4;ni++){
        const int r = wn*64 + ni*16 + lr;
        b[ni] = *(const bf16x8*)(Bs + r*64 + (c ^ (r&7))*8);
      }
      #pragma unroll
      for (int mi=0;mi<4;mi++){
        #pragma unroll
        for (int ni=0;ni<4;ni++)
          acc[mi][ni] = __builtin_amdgcn_mfma_f32_16x16x32_bf16(a[mi], b[ni], acc[mi][ni],0,0,0);
      }
    }
  }

  const int l4 = lq * 4;
  #pragma unroll
  for (int mi=0;mi<4;mi++){
    #pragma unroll
    for (int r=0;r<4;r++){
      const int pos = m0 + wm*64 + mi*16 + l4 + r;
      if (pos < rowEnd){
        u16* prow = part + (size_t)pos * HID;
        #pragma unroll
        for (int ni=0;ni<4;ni++){
          const int n = n0 + wn*64 + ni*16 + lr;
          prow[n] = f2bf(acc[mi][ni][r]);
        }
      }
    }
  }
}

// ---------------- combine: out[tok] = part[p0] + part[p1] ----------------
__global__ __launch_bounds__(256) void moe_combine(const u16* __restrict__ part,
                                                   const int* __restrict__ pos_of,
                                                   float* __restrict__ out){
  const int tok = blockIdx.x;
  const int p0 = pos_of[tok*2];
  const int p1 = pos_of[tok*2+1];
  const int h = threadIdx.x * 8;
  const u16x8 a = *(const u16x8*)(part + (size_t)p0 * HID + h);
  const u16x8 b = *(const u16x8*)(part + (size_t)p1 * HID + h);
  float4 o0, o1;
  o0.x = bf2f(a[0]) + bf2f(b[0]);
  o0.y = bf2f(a[1]) + bf2f(b[1]);
  o0.z = bf2f(a[2]) + bf2f(b[2]);
  o0.w = bf2f(a[3]) + bf2f(b[3]);
  o1.x = bf2f(a[4]) + bf2f(b[4]);
  o1.y = bf2f(a[5]) + bf2f(b[5]);
  o1.z = bf2f(a[6]) + bf2f(b[6]);
  o1.w = bf2f(a[7]) + bf2f(b[7]);
  float* orow = out + (size_t)tok * HID + h;
  *(float4*)orow = o0;
  *(float4*)(orow + 4) = o1;
}

// ---------------- host ----------------
extern "C" void kernel_launch(void* const* d_in, const int* in_sizes, int n_in,
                              void* d_out, int out_size, void* d_ws, size_t ws_size,
                              hipStream_t stream) {
  const float* x  = (const float*)d_in[0];
  const float* gw = (const float*)d_in[1];
  const float* w1 = (const float*)d_in[2];
  const float* w2 = (const float*)d_in[3];
  const float* w3 = (const float*)d_in[4];
  float* out = (float*)d_out;

  // workspace layout (no weight copies anymore)
  const size_t OFF_ROWTOK = 4096;
  const size_t OFF_ROWW   = OFF_ROWTOK + (size_t)CAP_ROWS*4;      // 70144
  const size_t OFF_TOP    = OFF_ROWW  + (size_t)CAP_ROWS*4;       // 136192
  const size_t OFF_TOKW   = OFF_TOP   + (size_t)T_TOK*2*4;        // 201728
  const size_t OFF_XB     = OFF_TOKW  + (size_t)T_TOK*2*4;        // 267264
  const size_t XB_BYTES   = (size_t)T_TOK*HID*2;                  // 33.55 MB
  const size_t OFF_ACT    = OFF_XB  + XB_BYTES;
  const size_t ACT_BYTES  = (size_t)CAP_ROWS*FFN_D*2;             // 135.3 MB
  const size_t OFF_PART   = OFF_ACT + ACT_BYTES;
  const size_t WS_NEED    = OFF_PART + (size_t)CAP_ROWS*HID*2;    // ~236.6 MB
  if (ws_size < WS_NEED) return;

  char* ws = (char*)d_ws;
  int*   meta    = (int*)ws;
  int*   row_tok = (int*)(ws + OFF_ROWTOK);
  float* row_w   = (float*)(ws + OFF_ROWW);
  int*   tok_top = (int*)(ws + OFF_TOP);
  float* tok_wt  = (float*)(ws + OFF_TOKW);   // pos_of aliases this after scatter
  u16*   xb      = (u16*)(ws + OFF_XB);
  u16*   act     = (u16*)(ws + OFF_ACT);
  u16*   part    = (u16*)(ws + OFF_PART);

  hipMemsetAsync(d_ws, 0, OFF_TOP, stream);   // meta + row_tok + row_w

  moe_cvt    <<<dim3(T_TOK*HID/2048), 256, 0, stream>>>(x, xb);
  moe_route  <<<dim3(T_TOK/4),        256, 0, stream>>>(x, gw, meta, tok_top, tok_wt);
  moe_prefix <<<1, 1, 0, stream>>>(meta);
  moe_scatter<<<dim3(T_TOK*2/256),    256, 0, stream>>>(tok_top, tok_wt, meta, row_tok, row_w);

  moe_up_f   <<<dim3(FFN_D/64, MAX_TILES), 256, 0, stream>>>(xb, w1, w3, act, meta, row_tok, row_w);
  moe_down_f <<<dim3(HID/128, MAX_TILES),  256, 0, stream>>>(act, w2, part, meta);
  moe_combine<<<dim3(T_TOK), 256, 0, stream>>>(part, (const int*)tok_wt, out);
}